// Round 1
// baseline (760.499 us; speedup 1.0000x reference)
//
#include <hip/hip_runtime.h>

#define NB 100000
#define F_IN 128
#define H1 32
#define H2 16

__global__ void k_init_deg(float* deg, int n) {
    int i = blockIdx.x * blockDim.x + threadIdx.x;
    if (i < n) deg[i] = 1.0f;  // self loop
}

__global__ void k_count_deg(const int* __restrict__ dst, int E, float* deg) {
    int e = blockIdx.x * blockDim.x + threadIdx.x;
    if (e < E) atomicAdd(&deg[dst[e]], 1.0f);
}

__global__ void k_rsqrt(float* deg, int n) {
    int i = blockIdx.x * blockDim.x + threadIdx.x;
    if (i < n) deg[i] = rsqrtf(deg[i]);
}

// g1[v,j] = dinv[v] * sum_k x[v,k] * W1[k,j];  acc1 initialized to g1 (self-loop term)
__global__ void k_gemm1(const float* __restrict__ x, const float* __restrict__ W1,
                        const float* __restrict__ dinv,
                        float* __restrict__ g1, float* __restrict__ acc1, int n) {
    __shared__ float Wl[F_IN * H1];  // 16 KB
    for (int t = threadIdx.x; t < F_IN * H1; t += blockDim.x) Wl[t] = W1[t];
    __syncthreads();
    int idx = blockIdx.x * blockDim.x + threadIdx.x;
    int node = idx >> 5, j = idx & 31;
    if (node < n) {
        const float* xr = x + (size_t)node * F_IN;
        float s = 0.f;
        #pragma unroll 8
        for (int k = 0; k < F_IN; ++k) s += xr[k] * Wl[k * H1 + j];
        float v = dinv[node] * s;
        g1[idx] = v;
        acc1[idx] = v;
    }
}

__global__ void k_scatter32(const int* __restrict__ src, const int* __restrict__ dst,
                            int total, const float* __restrict__ g, float* acc) {
    int idx = blockIdx.x * blockDim.x + threadIdx.x;
    if (idx >= total) return;
    int e = idx >> 5, j = idx & 31;
    int s = src[e], d = dst[e];
    atomicAdd(&acc[(size_t)d * H1 + j], g[(size_t)s * H1 + j]);
}

__global__ void k_relu1(float* acc, const float* __restrict__ dinv,
                        const float* __restrict__ b1, int total) {
    int idx = blockIdx.x * blockDim.x + threadIdx.x;
    if (idx < total) {
        int v = idx >> 5, j = idx & 31;
        float t = dinv[v] * acc[idx] + b1[j];
        acc[idx] = t > 0.f ? t : 0.f;
    }
}

// g2[v,j] = dinv[v] * sum_k h1[v,k] * W2[k,j]; acc2 = g2
__global__ void k_gemm2(const float* __restrict__ h1, const float* __restrict__ W2,
                        const float* __restrict__ dinv,
                        float* __restrict__ g2, float* __restrict__ acc2, int n) {
    __shared__ float Wl[H1 * H2];  // 2 KB
    for (int t = threadIdx.x; t < H1 * H2; t += blockDim.x) Wl[t] = W2[t];
    __syncthreads();
    int idx = blockIdx.x * blockDim.x + threadIdx.x;
    int node = idx >> 4, j = idx & 15;
    if (node < n) {
        const float* hr = h1 + (size_t)node * H1;
        float s = 0.f;
        #pragma unroll
        for (int k = 0; k < H1; ++k) s += hr[k] * Wl[k * H2 + j];
        float v = dinv[node] * s;
        g2[idx] = v;
        acc2[idx] = v;
    }
}

__global__ void k_scatter16(const int* __restrict__ src, const int* __restrict__ dst,
                            int total, const float* __restrict__ g, float* acc) {
    int idx = blockIdx.x * blockDim.x + threadIdx.x;
    if (idx >= total) return;
    int e = idx >> 4, j = idx & 15;
    int s = src[e], d = dst[e];
    atomicAdd(&acc[(size_t)d * H2 + j], g[(size_t)s * H2 + j]);
}

// out[v] = sum_j relu(dinv[v]*acc2[v,j] + b2[j]) * Wo[j] + bo
__global__ void k_final(const float* __restrict__ acc2, const float* __restrict__ dinv,
                        const float* __restrict__ b2, const float* __restrict__ Wo,
                        const float* __restrict__ bo, float* __restrict__ out, int n) {
    int v = blockIdx.x * blockDim.x + threadIdx.x;
    if (v < n) {
        float dv = dinv[v];
        float s = 0.f;
        #pragma unroll
        for (int j = 0; j < H2; ++j) {
            float t = dv * acc2[(size_t)v * H2 + j] + b2[j];
            s += (t > 0.f ? t : 0.f) * Wo[j];
        }
        out[v] = s + bo[0];
    }
}

extern "C" void kernel_launch(void* const* d_in, const int* in_sizes, int n_in,
                              void* d_out, int out_size, void* d_ws, size_t ws_size,
                              hipStream_t stream) {
    const float* x  = (const float*)d_in[0];
    const int*   ei = (const int*)d_in[1];
    const float* W1 = (const float*)d_in[2];
    const float* b1 = (const float*)d_in[3];
    const float* W2 = (const float*)d_in[4];
    const float* b2 = (const float*)d_in[5];
    const float* Wo = (const float*)d_in[6];
    const float* bo = (const float*)d_in[7];
    float* out = (float*)d_out;

    const int n = in_sizes[0] / F_IN;   // 100000
    const int E = in_sizes[1] / 2;      // 3200000
    const int* src = ei;
    const int* dst = ei + E;

    char* ws = (char*)d_ws;
    float* deg = (float*)ws;                                   // n floats; becomes dinv
    size_t off = (((size_t)n * 4) + 255) & ~(size_t)255;
    float* g1   = (float*)(ws + off);                          // n*32 floats
    float* acc1 = (float*)(ws + off + (size_t)n * H1 * 4);     // n*32 floats
    float* g2   = g1;                                          // n*16 floats (reuse)
    float* acc2 = g1 + (size_t)n * H2;                         // n*16 floats (reuse)
    float* h1   = acc1;                                        // relu in-place

    const int B = 256;
    k_init_deg<<<(n + B - 1) / B, B, 0, stream>>>(deg, n);
    k_count_deg<<<(E + B - 1) / B, B, 0, stream>>>(dst, E, deg);
    k_rsqrt<<<(n + B - 1) / B, B, 0, stream>>>(deg, n);

    int t1 = n * H1;
    k_gemm1<<<(t1 + B - 1) / B, B, 0, stream>>>(x, W1, deg, g1, acc1, n);
    int s1 = E * H1;  // 102,400,000 < 2^31
    k_scatter32<<<(s1 + B - 1) / B, B, 0, stream>>>(src, dst, s1, g1, acc1);
    k_relu1<<<(t1 + B - 1) / B, B, 0, stream>>>(acc1, deg, b1, t1);

    int t2 = n * H2;
    k_gemm2<<<(t2 + B - 1) / B, B, 0, stream>>>(h1, W2, deg, g2, acc2, n);
    int s2 = E * H2;
    k_scatter16<<<(s2 + B - 1) / B, B, 0, stream>>>(src, dst, s2, g2, acc2);

    k_final<<<(n + B - 1) / B, B, 0, stream>>>(acc2, deg, b2, Wo, bo, out, n);
}

// Round 2
// 730.707 us; speedup vs baseline: 1.0408x; 1.0408x over previous
//
#include <hip/hip_runtime.h>

#define F_IN 128
#define H1 32
#define H2 16
#define SCAN_CHUNK 1024   // elements per scan block (256 threads x 4)

__global__ void k_zero(int* p, int n) {
    int i = blockIdx.x * blockDim.x + threadIdx.x;
    if (i < n) p[i] = 0;
}

__global__ void k_hist(const int* __restrict__ dst, int E, int* __restrict__ cnt) {
    int e = blockIdx.x * blockDim.x + threadIdx.x;
    if (e < E) atomicAdd(&cnt[dst[e]], 1);
}

// per-block exclusive scan of cnt -> rowptr, block totals -> bsum
__global__ void k_scan1(const int* __restrict__ cnt, int n,
                        int* __restrict__ rowptr, int* __restrict__ bsum) {
    __shared__ int tsum[256];
    int t = threadIdx.x;
    int base = blockIdx.x * SCAN_CHUNK + t * 4;
    int v[4]; int s = 0;
    #pragma unroll
    for (int i = 0; i < 4; ++i) {
        v[i] = s;
        int idx = base + i;
        s += (idx < n) ? cnt[idx] : 0;
    }
    tsum[t] = s;
    __syncthreads();
    #pragma unroll
    for (int off = 1; off < 256; off <<= 1) {
        int x = (t >= off) ? tsum[t - off] : 0;
        __syncthreads();
        tsum[t] += x;
        __syncthreads();
    }
    int texcl = tsum[t] - s;
    #pragma unroll
    for (int i = 0; i < 4; ++i) {
        int idx = base + i;
        if (idx < n) rowptr[idx] = texcl + v[i];
    }
    if (t == 255) bsum[blockIdx.x] = tsum[255];
}

// single-block exclusive scan of block sums (nb <= 256)
__global__ void k_scan2(int* __restrict__ bsum, int nb) {
    __shared__ int sh[256];
    int t = threadIdx.x;
    int own = (t < nb) ? bsum[t] : 0;
    sh[t] = own;
    __syncthreads();
    #pragma unroll
    for (int off = 1; off < 256; off <<= 1) {
        int x = (t >= off) ? sh[t - off] : 0;
        __syncthreads();
        sh[t] += x;
        __syncthreads();
    }
    if (t < nb) bsum[t] = sh[t] - own;
}

// add block offsets; emit cursor copy, dinv, rowptr[n]
__global__ void k_scan3(int* __restrict__ rowptr, const int* __restrict__ bsum,
                        const int* __restrict__ cnt, int n, int E,
                        int* __restrict__ cursor, float* __restrict__ dinv) {
    int i = blockIdx.x * blockDim.x + threadIdx.x;
    if (i < n) {
        int r = rowptr[i] + bsum[i >> 10];
        rowptr[i] = r;
        cursor[i] = r;
        dinv[i] = rsqrtf((float)(cnt[i] + 1));
        if (i == 0) rowptr[n] = E;
    }
}

__global__ void k_fill(const int* __restrict__ src, const int* __restrict__ dst, int E,
                       int* __restrict__ cursor, int* __restrict__ perm) {
    int e = blockIdx.x * blockDim.x + threadIdx.x;
    if (e < E) {
        int pos = atomicAdd(&cursor[dst[e]], 1);
        perm[pos] = src[e];
    }
}

// g1[v,j] = dinv[v] * sum_k x[v,k] * W1[k,j]
__global__ void k_gemm1(const float* __restrict__ x, const float* __restrict__ W1,
                        const float* __restrict__ dinv, float* __restrict__ g1, int n) {
    __shared__ float Wl[F_IN * H1];  // 16 KB
    for (int t = threadIdx.x; t < F_IN * H1; t += blockDim.x) Wl[t] = W1[t];
    __syncthreads();
    int idx = blockIdx.x * blockDim.x + threadIdx.x;
    int node = idx >> 5, j = idx & 31;
    if (node < n) {
        const float* xr = x + (size_t)node * F_IN;
        float s = 0.f;
        #pragma unroll 8
        for (int k = 0; k < F_IN; ++k) s += xr[k] * Wl[k * H1 + j];
        g1[idx] = dinv[node] * s;
    }
}

// one 64-lane wave per node: lanes = 2 edge-slots x 32 features
// h1[v,j] = relu(dinv[v] * (g1[v,j] + sum_{u->v} g1[u,j]) + b1[j])
__global__ void k_agg1(const int* __restrict__ rowptr, const int* __restrict__ perm,
                       const float* __restrict__ g, const float* __restrict__ dinv,
                       const float* __restrict__ b1, float* __restrict__ h1, int n) {
    int wid = (blockIdx.x * blockDim.x + threadIdx.x) >> 6;
    if (wid >= n) return;
    int lane = threadIdx.x & 63;
    int j = lane & 31, slot = lane >> 5;
    int beg = rowptr[wid], end = rowptr[wid + 1];
    float acc = (slot == 0) ? g[(size_t)wid * H1 + j] : 0.f;  // self loop
    for (int e = beg + slot; e < end; e += 2)
        acc += g[(size_t)perm[e] * H1 + j];
    acc += __shfl_down(acc, 32);
    if (slot == 0) {
        float t = dinv[wid] * acc + b1[j];
        h1[(size_t)wid * H1 + j] = t > 0.f ? t : 0.f;
    }
}

// g2[v,j] = dinv[v] * sum_k h1[v,k] * W2[k,j]
__global__ void k_gemm2(const float* __restrict__ h1, const float* __restrict__ W2,
                        const float* __restrict__ dinv, float* __restrict__ g2, int n) {
    __shared__ float Wl[H1 * H2];  // 2 KB
    for (int t = threadIdx.x; t < H1 * H2; t += blockDim.x) Wl[t] = W2[t];
    __syncthreads();
    int idx = blockIdx.x * blockDim.x + threadIdx.x;
    int node = idx >> 4, j = idx & 15;
    if (node < n) {
        const float* hr = h1 + (size_t)node * H1;
        float s = 0.f;
        #pragma unroll
        for (int k = 0; k < H1; ++k) s += hr[k] * Wl[k * H2 + j];
        g2[idx] = dinv[node] * s;
    }
}

// one wave per node: lanes = 4 edge-slots x 16 features; fused final head
// out[v] = sum_j relu(dinv[v]*(g2[v,j]+sum_u g2[u,j]) + b2[j]) * Wo[j] + bo
__global__ void k_agg2(const int* __restrict__ rowptr, const int* __restrict__ perm,
                       const float* __restrict__ g2, const float* __restrict__ dinv,
                       const float* __restrict__ b2, const float* __restrict__ Wo,
                       const float* __restrict__ bo, float* __restrict__ out, int n) {
    int wid = (blockIdx.x * blockDim.x + threadIdx.x) >> 6;
    if (wid >= n) return;
    int lane = threadIdx.x & 63;
    int j = lane & 15, slot = lane >> 4;
    int beg = rowptr[wid], end = rowptr[wid + 1];
    float acc = (slot == 0) ? g2[(size_t)wid * H2 + j] : 0.f;  // self loop
    for (int e = beg + slot; e < end; e += 4)
        acc += g2[(size_t)perm[e] * H2 + j];
    acc += __shfl_down(acc, 32);
    acc += __shfl_down(acc, 16);
    // lanes 0..15 hold the aggregate for feature j
    float t = dinv[wid] * acc + b2[j];
    t = (t > 0.f ? t : 0.f) * Wo[j];
    t += __shfl_down(t, 8);
    t += __shfl_down(t, 4);
    t += __shfl_down(t, 2);
    t += __shfl_down(t, 1);
    if (lane == 0) out[wid] = t + bo[0];
}

extern "C" void kernel_launch(void* const* d_in, const int* in_sizes, int n_in,
                              void* d_out, int out_size, void* d_ws, size_t ws_size,
                              hipStream_t stream) {
    const float* x  = (const float*)d_in[0];
    const int*   ei = (const int*)d_in[1];
    const float* W1 = (const float*)d_in[2];
    const float* b1 = (const float*)d_in[3];
    const float* W2 = (const float*)d_in[4];
    const float* b2 = (const float*)d_in[5];
    const float* Wo = (const float*)d_in[6];
    const float* bo = (const float*)d_in[7];
    float* out = (float*)d_out;

    const int n = in_sizes[0] / F_IN;   // 100000
    const int E = in_sizes[1] / 2;      // 3200000
    const int* src = ei;
    const int* dst = ei + E;

    auto align = [](size_t s) { return (s + 255) & ~(size_t)255; };
    char* ws = (char*)d_ws;
    size_t o = 0;
    int*   cnt    = (int*)(ws + o); o += align((size_t)n * 4);
    int*   rowptr = (int*)(ws + o); o += align((size_t)(n + 1) * 4);
    int*   cursor = (int*)(ws + o); o += align((size_t)n * 4);
    float* dinv   = (float*)(ws + o); o += align((size_t)n * 4);
    int*   bsum   = (int*)(ws + o); o += align(256 * 4);
    int*   perm   = (int*)(ws + o); o += align((size_t)E * 4);
    float* g1     = (float*)(ws + o); o += align((size_t)n * H1 * 4);
    float* h1     = (float*)(ws + o); o += align((size_t)n * H1 * 4);
    float* g2     = g1;  // reuse (g1 dead after k_agg1)

    const int B = 256;
    const int nScanBlocks = (n + SCAN_CHUNK - 1) / SCAN_CHUNK;  // 98 <= 256

    k_zero <<<(n + B - 1) / B, B, 0, stream>>>(cnt, n);
    k_hist <<<(E + B - 1) / B, B, 0, stream>>>(dst, E, cnt);
    k_scan1<<<nScanBlocks, B, 0, stream>>>(cnt, n, rowptr, bsum);
    k_scan2<<<1, B, 0, stream>>>(bsum, nScanBlocks);
    k_scan3<<<(n + B - 1) / B, B, 0, stream>>>(rowptr, bsum, cnt, n, E, cursor, dinv);
    k_fill <<<(E + B - 1) / B, B, 0, stream>>>(src, dst, E, cursor, perm);

    int t1 = n * H1;
    k_gemm1<<<(t1 + B - 1) / B, B, 0, stream>>>(x, W1, dinv, g1, n);
    k_agg1 <<<(n * 64 + B - 1) / B, B, 0, stream>>>(rowptr, perm, g1, dinv, b1, h1, n);

    int t2 = n * H2;
    k_gemm2<<<(t2 + B - 1) / B, B, 0, stream>>>(h1, W2, dinv, g2, n);
    k_agg2 <<<(n * 64 + B - 1) / B, B, 0, stream>>>(rowptr, perm, g2, dinv, b2, Wo, bo, out, n);
}